// Round 4
// baseline (4827.950 us; speedup 1.0000x reference)
//
#include <hip/hip_runtime.h>
#include <math.h>

#define B_ 128
#define L_ 30
#define M_ 10
#define H_ 256
#define VN_ 32000
#define VCH 10
#define VITER 25     // (VN/VCH)/128

typedef __bf16 bf16;
typedef bf16 bf16x8 __attribute__((ext_vector_type(8)));
typedef float f32x4 __attribute__((ext_vector_type(4)));

#define MFMA(a,b,c) __builtin_amdgcn_mfma_f32_16x16x32_bf16(a, b, c, 0, 0, 0)

__device__ __forceinline__ float rcpf(float x) { return __builtin_amdgcn_rcpf(x); }
__device__ __forceinline__ float sigf(float x) { return rcpf(1.f + __expf(-x)); }
__device__ __forceinline__ float ftanh(float x) {
  float e = __expf(2.f * x);
  return 1.f - 2.f * rcpf(e + 1.f);
}
__device__ __forceinline__ float u2lo(unsigned w) { return __builtin_bit_cast(float, w << 16); }
__device__ __forceinline__ float u2hi(unsigned w) { return __builtin_bit_cast(float, w & 0xffff0000u); }
__device__ __forceinline__ unsigned packbf2(float a, float b) {
  unsigned short lo = __builtin_bit_cast(unsigned short, (bf16)a);
  unsigned short hi = __builtin_bit_cast(unsigned short, (bf16)b);
  return (unsigned)lo | ((unsigned)hi << 16);
}

// ---------------- LDS offsets (bytes) for k_loop ----------------
#define X2O    0        // bf16 [16][512] swz  (prev_emb | prev_h)
#define CAT5O  16384    // bf16 [16][1280] swz (cHN,cHK,cHV,cMK,cMV); aliased below
#define DAO    16384    // f32 [16][128]  (alias, pre-cat5 lifetime)
#define DBO    24576    // f32 [16][128]  (alias)
#define GATO   57344    // bf16 [16][1024] linear (raw gates GEMM out)
#define HBFO   90112    // bf16 [16][256] swz (h)
#define HV3O   98304    // bf16 [48][256] swz (hN|hK|hV of latest slot)
#define SWO    122880   // f32 [16][96]
#define ACAO   129024   // f32 [16][96]
#define SWMO   135168   // f32 [16][32] (mem-attn weights; also gt scratch)
#define BCO    137216   // f32 [256]  b_ct
#define BIO    138240   // f32 [1024] b_ih+b_hh
#define BHO    142336   // f32 [96]   b_hn|b_hk|b_hv (padded 32)
#define BMO    142720   // f32 [32]   b_mk|b_mv
#define BGO    142848   // f32 [1]    b_g
#define LDSSZ  143360

// ---------------------------------------------------------------- weight prep
// All MFMA B-tiles stored as [tile][lane][8] bf16 so a B-fragment is one
// coalesced 16B/lane load directly from L2 (no LDS staging for B).
__global__ __launch_bounds__(256) void k_prep(
    const float* W_ct, const float* W_ih, const float* W_hh,
    const float* W_n, const float* W_k, const float* W_v, const float* W_nv,
    const float* W_hn, const float* W_hk, const float* W_hv,
    const float* W_mk, const float* W_mv,
    bf16* BgT, bf16* BcT, bf16* BnkvT, bf16* Wmt, bf16* Whdt, bf16* Whd0, bf16* Wnvb) {
  int stride = gridDim.x * blockDim.x;
  int base = blockIdx.x * blockDim.x + threadIdx.x;
  // gates: N=1024, K=512, tiles [n16(64)][k32(16)]
  for (int i = base; i < 64*16*512; i += stride) {
    int t8 = i & 511, tile = i >> 9;
    int k32 = tile & 15, n16 = tile >> 4;
    int lane = t8 >> 3, j = t8 & 7;
    int n = n16*16 + (lane & 15);
    int k = k32*32 + (lane >> 4)*8 + j;
    BgT[i] = (bf16)(k < 256 ? W_ih[n*256 + k] : W_hh[n*256 + k - 256]);
  }
  // c0: N=256, K=1280, tiles [n16(16)][k32(40)]
  for (int i = base; i < 16*40*512; i += stride) {
    int t8 = i & 511, tile = i >> 9;
    int k32 = tile % 40, n16 = tile / 40;
    int lane = t8 >> 3, j = t8 & 7;
    int n = n16*16 + (lane & 15);
    int k = k32*32 + (lane >> 4)*8 + j;
    BcT[i] = (bf16)W_ct[n*1280 + k];
  }
  // hnkv: N=768, K=256, tiles [n16(48)][k32(8)]
  for (int i = base; i < 48*8*512; i += stride) {
    int t8 = i & 511, tile = i >> 9;
    int k32 = tile & 7, n16 = tile >> 3;
    int lane = t8 >> 3, j = t8 & 7;
    int n = n16*16 + (lane & 15);
    int k = k32*32 + (lane >> 4)*8 + j;
    float val = (n < 256) ? W_n[n*256+k] : (n < 512) ? W_k[(n-256)*256+k] : W_v[(n-512)*256+k];
    BnkvT[i] = (bf16)val;
  }
  // mem-attn: N=32 (mk rows 0-9 @n16=0, mv rows 0-9 @n16=1), K=1024, tiles [n16(2)][k32(32)]
  for (int i = base; i < 2*32*512; i += stride) {
    int t8 = i & 511, tile = i >> 9;
    int k32 = tile & 31, n16 = tile >> 5;
    int lane = t8 >> 3, j = t8 & 7;
    int m = lane & 15;
    int k = k32*32 + (lane >> 4)*8 + j;
    float v = (m < 10) ? (n16 == 0 ? W_mk[m*1024 + k] : W_mv[m*1024 + k]) : 0.f;
    Wmt[i] = (bf16)v;
  }
  // attn dA per-step slices: [di(30)][g(6)=X*2+n16][k32(8)] of W_hX[l][di*256+k]
  for (int i = base; i < 30*6*8*512; i += stride) {
    int t8 = i & 511, tile = i >> 9;
    int k32 = tile & 7, g = (tile >> 3) % 6, di = tile / 48;
    int lane = t8 >> 3, j = t8 & 7;
    int X = g >> 1, n16 = g & 1;
    int l = n16*16 + (lane & 15);
    int k = k32*32 + (lane >> 4)*8 + j;
    const float* W = (X == 0) ? W_hn : (X == 1) ? W_hk : W_hv;
    Whdt[i] = (bf16)((l < 30) ? W[l*7936 + di*256 + k] : 0.f);
  }
  // attn dB (j=0 slice): N=96 stacked, tiles [n16(6)][k32(8)]
  for (int i = base; i < 6*8*512; i += stride) {
    int t8 = i & 511, tile = i >> 9;
    int k32 = tile & 7, n16 = tile >> 3;
    int lane = t8 >> 3, j = t8 & 7;
    int n = n16*16 + (lane & 15);
    int X = n >> 5, l = n & 31;
    int k = k32*32 + (lane >> 4)*8 + j;
    const float* W = (X == 0) ? W_hn : (X == 1) ? W_hk : W_hv;
    Whd0[i] = (bf16)((l < 30) ? W[l*7936 + k] : 0.f);
  }
  for (int i = base; i < VN_*H_; i += stride) Wnvb[i] = (bf16)W_nv[i];
}

// ---------------------------------------------------------------- recurrence: 8 blocks x 16 batch rows
struct LoopP {
  const int *sentence, *keywords, *categories, *memsz;
  const float *emb;
  const bf16 *BgT, *BcT, *BnkvT, *Wmt, *Whdt, *Whd0;
  const float *b_ct, *b_ih, *b_hh, *b_hn, *b_hk, *b_hv, *b_mk, *b_mv, *W_g, *b_g;
  bf16* histG;       // [3][128][30][256] bf16
  bf16* membG;       // [2][128][10][256] bf16
  float* gt_all;     // [29][128]
  float* outg;       // [128][30]
};

__global__ __launch_bounds__(512) void k_loop(LoopP p) {
  extern __shared__ char sm[];
  int t = threadIdx.x, blk = blockIdx.x;
  int w = t >> 6, lane = t & 63;
  int b0 = blk * 16;

  // ===== init =====
  for (int i = t; i < 16*M_*H_; i += 512) {
    int bs = i / 2560, m = (i / 256) % 10, k = i & 255;
    int b = b0 + bs;
    int ms = p.memsz[b];
    int kw = p.keywords[b*M_ + m], cg = p.categories[b*M_ + m];
    float ke = (m < ms) ? p.emb[(size_t)kw*H_ + k] : 0.f;
    float ve = (m < ms) ? p.emb[(size_t)cg*H_ + k] : 0.f;
    p.membG[(size_t)(b*M_ + m)*H_ + k] = (bf16)ke;
    p.membG[(size_t)327680 + (size_t)(b*M_ + m)*H_ + k] = (bf16)ve;
  }
  for (int i = t; i < 4096; i += 512) {
    int bs = i >> 8, k = i & 255;
    int b = b0 + bs;
    int ms = p.memsz[b];
    float s = 0.f;
    for (int m = 0; m < M_; ++m) {
      if (m < ms)
        s += p.emb[(size_t)p.keywords[b*M_+m]*H_ + k] + p.emb[(size_t)p.categories[b*M_+m]*H_ + k];
    }
    float ih = s / (2.f * (float)ms);
    bf16 ihb = (bf16)ih;
    for (int X = 0; X < 3; ++X) {
      p.histG[((size_t)(X*128 + b)*L_)*H_ + k] = ihb;
      int row = X*16 + bs;
      *(bf16*)(sm + HV3O + ((row*512 + k*2) ^ ((row&7)<<4))) = ihb;
    }
    int s0 = p.sentence[b*L_];
    *(bf16*)(sm + X2O + ((bs*1024 + (256+k)*2) ^ ((bs&7)<<4))) = ihb;
    *(bf16*)(sm + X2O + ((bs*1024 + k*2) ^ ((bs&7)<<4))) = (bf16)p.emb[(size_t)s0*H_ + k];
  }
  if (t < 256) ((float*)(sm+BCO))[t] = p.b_ct[t];
  for (int i = t; i < 1024; i += 512) ((float*)(sm+BIO))[i] = p.b_ih[i] + p.b_hh[i];
  if (t < 96) {
    int X = t >> 5, l = t & 31;
    const float* bh = (X == 0) ? p.b_hn : (X == 1) ? p.b_hk : p.b_hv;
    ((float*)(sm+BHO))[t] = (l < 30) ? bh[l] : 0.f;
  }
  if (t < 32) {
    int m = t & 15;
    float v = 0.f;
    if (m < 10) v = (t < 16) ? p.b_mk[m] : p.b_mv[m];
    ((float*)(sm+BMO))[t] = v;
  }
  if (t == 0) ((float*)(sm+BGO))[0] = p.b_g[0];
  for (int i = t; i < 1536; i += 512) ((float*)(sm+ACAO))[i] = 0.f;
  if (t < 16) p.outg[(b0 + t)*L_] = 0.f;
  __syncthreads();

  for (int di = 1; di < L_; ++di) {
    // ---- region 1: gates GEMM (A1) + attn-logit GEMMs (A2) ----
    {
      f32x4 acc[8] = {};
      const bf16* Bg = p.BgT + (size_t)w*(8*16*512);
      for (int k32 = 0; k32 < 16; ++k32) {
        int kb = k32*64 + (lane>>4)*16;
        int row = lane & 15;
        bf16x8 a = *(const bf16x8*)(sm + X2O + ((row*1024 + kb) ^ ((row&7)<<4)));
        #pragma unroll
        for (int fj = 0; fj < 8; ++fj) {
          bf16x8 bv = *(const bf16x8*)(Bg + (size_t)(fj*16 + k32)*512 + lane*8);
          acc[fj] = MFMA(a, bv, acc[fj]);
        }
      }
      #pragma unroll
      for (int fj = 0; fj < 8; ++fj)
        #pragma unroll
        for (int r = 0; r < 4; ++r) {
          int bs = (lane>>4)*4 + r, n = w*128 + fj*16 + (lane&15);
          *(bf16*)(sm + GATO + bs*2048 + n*2) = (bf16)acc[fj][r];
        }
      for (int task = w; task < 12; task += 8) {
        f32x4 a2 = {};
        if (task < 6) {
          int X = task >> 1, n16 = task & 1;
          const bf16* Bt = p.Whdt + ((size_t)(di*6 + task)*8)*512;
          for (int k32 = 0; k32 < 8; ++k32) {
            int kb = k32*64 + (lane>>4)*16;
            int row = X*16 + (lane&15);
            bf16x8 a = *(const bf16x8*)(sm + HV3O + ((row*512 + kb) ^ ((row&7)<<4)));
            bf16x8 bv = *(const bf16x8*)(Bt + (size_t)k32*512 + lane*8);
            a2 = MFMA(a, bv, a2);
          }
          #pragma unroll
          for (int r = 0; r < 4; ++r) {
            int bs = (lane>>4)*4 + r;
            ((float*)(sm+DAO))[bs*128 + X*32 + n16*16 + (lane&15)] = a2[r];
          }
        } else {
          int n16 = task - 6;
          const bf16* Bt = p.Whd0 + ((size_t)n16*8)*512;
          for (int k32 = 0; k32 < 8; ++k32) {
            int kb = 512 + k32*64 + (lane>>4)*16;
            int row = lane & 15;
            bf16x8 a = *(const bf16x8*)(sm + X2O + ((row*1024 + kb) ^ ((row&7)<<4)));
            bf16x8 bv = *(const bf16x8*)(Bt + (size_t)k32*512 + lane*8);
            a2 = MFMA(a, bv, a2);
          }
          #pragma unroll
          for (int r = 0; r < 4; ++r) {
            int bs = (lane>>4)*4 + r;
            ((float*)(sm+DBO))[bs*128 + n16*16 + (lane&15)] = a2[r];
          }
        }
      }
    }
    __syncthreads();
    // ---- region 2: logits cleanup ----
    if (t < 480) {
      for (int q = t; q < 1440; q += 480) {
        int bs = q / 90, rem = q - bs*90, X = rem / 30, l = rem - X*30;
        int c = X*32 + l;
        float dA = ((float*)(sm+DAO))[bs*128 + c];
        float dB = ((float*)(sm+DBO))[bs*128 + c];
        float a = ((float*)(sm+ACAO))[bs*96 + c] + dA;
        ((float*)(sm+ACAO))[bs*96 + c] = a;
        ((float*)(sm+SWO))[bs*96 + c] = ftanh(a + dB + ((float*)(sm+BHO))[c]);
      }
    }
    __syncthreads();
    // ---- region 3: einsum cH + hist append (u32 pairs) ----
    for (int i = t; i < 6144; i += 512) {
      int X = i >> 11, rem = i & 2047, bs = rem >> 7, k2 = rem & 127;
      int b = b0 + bs;
      const float* swp = (const float*)(sm+SWO) + bs*96 + X*32;
      unsigned* hg = (unsigned*)p.histG + ((size_t)(X*128 + b)*L_)*128 + k2;
      float a0 = 0.f, a1 = 0.f;
      for (int l = 0; l < di-1; ++l) {
        unsigned u = hg[l*128];
        a0 = fmaf(swp[l], u2lo(u), a0);
        a1 = fmaf(swp[l], u2hi(u), a1);
      }
      int row = X*16 + bs;
      unsigned hv = *(const unsigned*)(sm + HV3O + ((row*512 + k2*4) ^ ((row&7)<<4)));
      a0 = fmaf(swp[di-1], u2lo(hv), a0);
      a1 = fmaf(swp[di-1], u2hi(hv), a1);
      hg[(di-1)*128] = hv;
      *(unsigned*)(sm + CAT5O + ((bs*2560 + X*512 + k2*4) ^ ((bs&7)<<4))) = packbf2(a0, a1);
    }
    __syncthreads();
    // ---- region 4: memory-attn logit GEMM (waves 0,1) ----
    if (w < 2) {
      f32x4 a4 = {};
      const bf16* Bt = p.Wmt + ((size_t)w*32)*512;
      for (int k32 = 0; k32 < 32; ++k32) {
        int row = lane & 15;
        bf16x8 a;
        if (k32 < 8) {
          int kb = 512 + k32*64 + (lane>>4)*16;
          a = *(const bf16x8*)(sm + X2O + ((row*1024 + kb) ^ ((row&7)<<4)));
        } else {
          int kb = (k32-8)*64 + (lane>>4)*16;
          a = *(const bf16x8*)(sm + CAT5O + ((row*2560 + kb) ^ ((row&7)<<4)));
        }
        bf16x8 bv = *(const bf16x8*)(Bt + (size_t)k32*512 + lane*8);
        a4 = MFMA(a, bv, a4);
      }
      int m = lane & 15;
      if (m < 10) {
        #pragma unroll
        for (int r = 0; r < 4; ++r) {
          int bs = (lane>>4)*4 + r;
          ((float*)(sm+SWMO))[bs*32 + w*16 + m] = ftanh(a4[r] + ((float*)(sm+BMO))[w*16 + m]);
        }
      }
    }
    __syncthreads();
    // ---- region 5: cMK/cMV + next-token emb gather ----
    for (int i = t; i < 4096; i += 512) {
      int X = i >> 11, rem = i & 2047, bs = rem >> 7, k2 = rem & 127;
      int b = b0 + bs;
      const unsigned* mg = (const unsigned*)p.membG + (size_t)X*163840 + (size_t)b*M_*128 + k2;
      const float* swm = (const float*)(sm+SWMO) + bs*32 + X*16;
      float c0 = 0.f, c1 = 0.f;
      #pragma unroll
      for (int m = 0; m < M_; ++m) {
        unsigned u = mg[m*128];
        c0 = fmaf(swm[m], u2lo(u), c0);
        c1 = fmaf(swm[m], u2hi(u), c1);
      }
      *(unsigned*)(sm + CAT5O + ((bs*2560 + 1536 + X*512 + k2*4) ^ ((bs&7)<<4))) = packbf2(c0, c1);
    }
    for (int i = t; i < 2048; i += 512) {
      int bs = i >> 7, k2 = i & 127;
      int b = b0 + bs;
      int tok = p.sentence[b*L_ + di];
      const float* e = p.emb + (size_t)tok*H_ + k2*2;
      *(unsigned*)(sm + X2O + ((bs*1024 + k2*4) ^ ((bs&7)<<4))) = packbf2(e[0], e[1]);
    }
    __syncthreads();
    // ---- region 6: c0 GEMM + LSTM cell (in-reg epilogue) ----
    {
      f32x4 acc[2] = {};
      const bf16* Bt = p.BcT + ((size_t)(2*w)*40)*512;
      for (int k32 = 0; k32 < 40; ++k32) {
        int kb = k32*64 + (lane>>4)*16;
        int row = lane & 15;
        bf16x8 a = *(const bf16x8*)(sm + CAT5O + ((row*2560 + kb) ^ ((row&7)<<4)));
        #pragma unroll
        for (int fj = 0; fj < 2; ++fj) {
          bf16x8 bv = *(const bf16x8*)(Bt + (size_t)(fj*40 + k32)*512 + lane*8);
          acc[fj] = MFMA(a, bv, acc[fj]);
        }
      }
      #pragma unroll
      for (int fj = 0; fj < 2; ++fj)
        #pragma unroll
        for (int r = 0; r < 4; ++r) {
          int bs = (lane>>4)*4 + r;
          int n = w*32 + fj*16 + (lane&15);
          const bf16* g = (const bf16*)(sm + GATO) + bs*1024;
          const float* bI = (const float*)(sm+BIO);
          float gi = (float)g[n]     + bI[n];
          float gf = (float)g[256+n] + bI[256+n];
          float gg = (float)g[512+n] + bI[512+n];
          float go = (float)g[768+n] + bI[768+n];
          float c0v = acc[fj][r] + ((const float*)(sm+BCO))[n];
          float cc = sigf(gf)*c0v + sigf(gi)*ftanh(gg);
          float h = sigf(go)*ftanh(cc);
          bf16 hb = (bf16)h;
          *(bf16*)(sm + HBFO + ((bs*512 + n*2) ^ ((bs&7)<<4))) = hb;
          *(bf16*)(sm + X2O + ((bs*1024 + (256+n)*2) ^ ((bs&7)<<4))) = hb;
        }
    }
    __syncthreads();
    // ---- region 7: hN/hK/hV GEMM -> hv3 ----
    {
      f32x4 acc[6] = {};
      const bf16* Bt = p.BnkvT + ((size_t)(w*6)*8)*512;
      for (int k32 = 0; k32 < 8; ++k32) {
        int kb = k32*64 + (lane>>4)*16;
        int row = lane & 15;
        bf16x8 a = *(const bf16x8*)(sm + HBFO + ((row*512 + kb) ^ ((row&7)<<4)));
        #pragma unroll
        for (int fj = 0; fj < 6; ++fj) {
          bf16x8 bv = *(const bf16x8*)(Bt + (size_t)(fj*8 + k32)*512 + lane*8);
          acc[fj] = MFMA(a, bv, acc[fj]);
        }
      }
      #pragma unroll
      for (int fj = 0; fj < 6; ++fj)
        #pragma unroll
        for (int r = 0; r < 4; ++r) {
          int bs = (lane>>4)*4 + r;
          int n = (w*6 + fj)*16 + (lane&15);
          int X = n >> 8, k = n & 255;
          int row = X*16 + bs;
          *(bf16*)(sm + HV3O + ((row*512 + k*2) ^ ((row&7)<<4))) = (bf16)acc[fj][r];
        }
    }
    __syncthreads();
    // ---- gt ----
    {
      int bs = t >> 5, q = t & 31;
      float s = 0.f;
      #pragma unroll
      for (int j = 0; j < 8; ++j) {
        int k = q*8 + j;
        bf16 hb = *(const bf16*)(sm + HBFO + ((bs*512 + k*2) ^ ((bs&7)<<4)));
        s = fmaf((float)hb, p.W_g[k], s);
      }
      ((float*)(sm+SWMO))[bs*32 + q] = s;
    }
    __syncthreads();
    if (t < 16) {
      float s = 0.f;
      const float* r = (const float*)(sm+SWMO) + t*32;
      #pragma unroll
      for (int q = 0; q < 32; ++q) s += r[q];
      float g = sigf(s + ((const float*)(sm+BGO))[0]);
      int b = b0 + t;
      p.gt_all[(di-1)*B_ + b] = g;
      p.outg[b*L_ + di] = g;
    }
    __syncthreads();
  }
  // post-loop: hv3 -> hist slot 29
  for (int i = t; i < 3*4096; i += 512) {
    int X = i >> 12, rem = i & 4095, bs = rem >> 8, k = rem & 255;
    int b = b0 + bs;
    int row = X*16 + bs;
    bf16 v = *(const bf16*)(sm + HV3O + ((row*512 + k*2) ^ ((row&7)<<4)));
    p.histG[(((size_t)(X*128 + b)*L_) + 29)*H_ + k] = v;
  }
}

// ---------------------------------------------------------------- batched vocab GEMM + streaming LSE
__global__ __launch_bounds__(256) void k_vocab(
    const bf16* hist0, const bf16* Wnvb, const float* b_nv, float2* pmps) {
  extern __shared__ char smv[];
  char* Al = smv;             // 128 x 256 bf16, swizzled
  char* Bl = smv + 65536;     // 128 x 256 bf16, swizzled
  int blk = blockIdx.x;
  int tile = blk / VCH, ch = blk - tile*VCH;
  int t = threadIdx.x, wid = t >> 6, lane = t & 63;
  for (int i = t; i < 128*32; i += 256) {
    int r = i >> 5, c8 = i & 31;
    int4 v = *(const int4*)(hist0 + ((size_t)r*L_ + tile + 1)*H_ + c8*8);
    *(int4*)(Al + ((r*512 + c8*16) ^ ((r&7)<<4))) = v;
  }
  __syncthreads();
  bf16x8 afr[8][2];
  #pragma unroll
  for (int kk = 0; kk < 8; ++kk) {
    int kb2 = kk*64 + (lane>>4)*16;
    #pragma unroll
    for (int fi = 0; fi < 2; ++fi) {
      int m = wid*32 + fi*16 + (lane & 15);
      afr[kk][fi] = *(const bf16x8*)(Al + ((m*512 + kb2) ^ ((m&7)<<4)));
    }
  }
  float Mrun[2][4], Srun[2][4];
  #pragma unroll
  for (int fi = 0; fi < 2; ++fi)
    #pragma unroll
    for (int r = 0; r < 4; ++r) { Mrun[fi][r] = -1e30f; Srun[fi][r] = 0.f; }
  int v0 = ch * (VN_/VCH);
  for (int it = 0; it < VITER; ++it) {
    for (int i = t; i < 128*32; i += 256) {
      int r = i >> 5, c8 = i & 31;
      int4 v = *(const int4*)(Wnvb + (size_t)(v0 + it*128 + r)*H_ + c8*8);
      *(int4*)(Bl + ((r*512 + c8*16) ^ ((r&7)<<4))) = v;
    }
    __syncthreads();
    f32x4 acc[2][8] = {};
    #pragma unroll
    for (int kk = 0; kk < 8; ++kk) {
      int kb2 = kk*64 + (lane>>4)*16;
      bf16x8 bfr[8];
      #pragma unroll
      for (int fj = 0; fj < 8; ++fj) {
        int n = fj*16 + (lane & 15);
        bfr[fj] = *(const bf16x8*)(Bl + ((n*512 + kb2) ^ ((n&7)<<4)));
      }
      #pragma unroll
      for (int fi = 0; fi < 2; ++fi)
        #pragma unroll
        for (int fj = 0; fj < 8; ++fj)
          acc[fi][fj] = MFMA(afr[kk][fi], bfr[fj], acc[fi][fj]);
    }
    float bb[8];
    #pragma unroll
    for (int fj = 0; fj < 8; ++fj) bb[fj] = b_nv[v0 + it*128 + fj*16 + (lane & 15)];
    #pragma unroll
    for (int fi = 0; fi < 2; ++fi)
      #pragma unroll
      for (int r = 0; r < 4; ++r) {
        float mi = acc[fi][0][r] + bb[0];
        #pragma unroll
        for (int fj = 1; fj < 8; ++fj) mi = fmaxf(mi, acc[fi][fj][r] + bb[fj]);
        for (int o = 1; o < 16; o <<= 1) mi = fmaxf(mi, __shfl_xor(mi, o));
        float si = 0.f;
        #pragma unroll
        for (int fj = 0; fj < 8; ++fj) si += __expf(acc[fi][fj][r] + bb[fj] - mi);
        for (int o = 1; o < 16; o <<= 1) si += __shfl_xor(si, o);
        float M2 = fmaxf(Mrun[fi][r], mi);
        Srun[fi][r] = Srun[fi][r]*__expf(Mrun[fi][r] - M2) + si*__expf(mi - M2);
        Mrun[fi][r] = M2;
      }
    __syncthreads();
  }
  #pragma unroll
  for (int fi = 0; fi < 2; ++fi)
    #pragma unroll
    for (int r = 0; r < 4; ++r)
      if ((lane & 15) == 0) {
        int row = wid*32 + fi*16 + (lane>>4)*4 + r;
        int g = tile*128 + row;
        pmps[(size_t)g*VCH + ch] = make_float2(Mrun[fi][r], Srun[fi][r]);
      }
}

// ---------------------------------------------------------------- per-step loss combine
__global__ __launch_bounds__(128) void k_combine(
    const float2* pmps, const bf16* hist0, const float* W_nv, const float* b_nv,
    const float* gt_all, const int* sentence, float* loss_part) {
  __shared__ float red[128];
  int tile = blockIdx.x, bb = threadIdx.x;
  int g = tile*128 + bb;
  float M = -1e30f, Ssum = 0.f;
  #pragma unroll
  for (int c = 0; c < VCH; ++c) {
    float2 v = pmps[(size_t)g*VCH + c];
    float M2 = fmaxf(M, v.x);
    Ssum = Ssum*__expf(M - M2) + v.y*__expf(v.x - M2);
    M = M2;
  }
  int tok = sentence[bb*L_ + tile + 1];
  float z = b_nv[tok];
  const unsigned* hu = (const unsigned*)(hist0 + ((size_t)bb*L_ + tile + 1)*H_);
  const float* wr = W_nv + (size_t)tok*H_;
  #pragma unroll 8
  for (int k = 0; k < 128; ++k) {
    unsigned w2 = hu[k];
    z += u2lo(w2)*wr[2*k] + u2hi(w2)*wr[2*k + 1];
  }
  float term = -(z - M - __logf(Ssum) + __logf(gt_all[g]));
  red[bb] = term;
  __syncthreads();
  for (int o = 64; o > 0; o >>= 1) {
    if (bb < o) red[bb] += red[bb + o];
    __syncthreads();
  }
  if (bb == 0) loss_part[tile] = red[0];
}

__global__ __launch_bounds__(64) void k_fin(const float* lp, float* out) {
  int t = threadIdx.x;
  float v = (t < 29) ? lp[t] : 0.f;
  for (int o = 1; o < 64; o <<= 1) v += __shfl_xor(v, o);
  if (t == 0) out[0] = v;
}

// ---------------------------------------------------------------- launch
extern "C" void kernel_launch(void* const* d_in, const int* in_sizes, int n_in,
                              void* d_out, int out_size, void* d_ws, size_t ws_size,
                              hipStream_t stream) {
  const int* sentence  = (const int*)d_in[0];
  const int* keywords  = (const int*)d_in[1];
  const int* categories= (const int*)d_in[2];
  const int* memsz     = (const int*)d_in[3];
  const float* emb  = (const float*)d_in[5];
  const float* W_ct = (const float*)d_in[6];
  const float* b_ct = (const float*)d_in[7];
  const float* W_ih = (const float*)d_in[8];
  const float* W_hh = (const float*)d_in[9];
  const float* b_ih = (const float*)d_in[10];
  const float* b_hh = (const float*)d_in[11];
  const float* W_n  = (const float*)d_in[12];
  const float* W_k  = (const float*)d_in[13];
  const float* W_v  = (const float*)d_in[14];
  const float* W_nv = (const float*)d_in[15];
  const float* b_nv = (const float*)d_in[16];
  const float* W_g  = (const float*)d_in[17];
  const float* b_g  = (const float*)d_in[18];
  const float* W_hn = (const float*)d_in[19];
  const float* b_hn = (const float*)d_in[20];
  const float* W_hk = (const float*)d_in[21];
  const float* b_hk = (const float*)d_in[22];
  const float* W_hv = (const float*)d_in[23];
  const float* b_hv = (const float*)d_in[24];
  const float* W_mk = (const float*)d_in[25];
  const float* b_mk = (const float*)d_in[26];
  const float* W_mv = (const float*)d_in[27];
  const float* b_mv = (const float*)d_in[28];
  float* out = (float*)d_out;

  char* wsp = (char*)d_ws;
  size_t off = 0;
  auto alloc = [&](size_t bytes) -> void* {
    void* pp = wsp + off;
    off = (off + bytes + 255) & ~(size_t)255;
    return pp;
  };
  bf16* BgT   = (bf16*)alloc((size_t)64*16*512*2);
  bf16* BcT   = (bf16*)alloc((size_t)16*40*512*2);
  bf16* BnkvT = (bf16*)alloc((size_t)48*8*512*2);
  bf16* Wmt   = (bf16*)alloc((size_t)2*32*512*2);
  bf16* Whdt  = (bf16*)alloc((size_t)30*6*8*512*2);
  bf16* Whd0  = (bf16*)alloc((size_t)6*8*512*2);
  bf16* Wnvb  = (bf16*)alloc((size_t)VN_*H_*2);
  bf16* histG = (bf16*)alloc((size_t)3*128*L_*H_*2);
  bf16* membG = (bf16*)alloc((size_t)2*128*M_*H_*2);
  float* gt_all    = (float*)alloc((size_t)29*B_*4);
  float2* pmps     = (float2*)alloc((size_t)29*B_*VCH*8);
  float* loss_part = (float*)alloc(29*4);

  k_prep<<<1024, 256, 0, stream>>>(W_ct, W_ih, W_hh, W_n, W_k, W_v, W_nv,
      W_hn, W_hk, W_hv, W_mk, W_mv, BgT, BcT, BnkvT, Wmt, Whdt, Whd0, Wnvb);

  LoopP P;
  P.sentence = sentence; P.keywords = keywords; P.categories = categories; P.memsz = memsz;
  P.emb = emb;
  P.BgT = BgT; P.BcT = BcT; P.BnkvT = BnkvT; P.Wmt = Wmt; P.Whdt = Whdt; P.Whd0 = Whd0;
  P.b_ct = b_ct; P.b_ih = b_ih; P.b_hh = b_hh;
  P.b_hn = b_hn; P.b_hk = b_hk; P.b_hv = b_hv;
  P.b_mk = b_mk; P.b_mv = b_mv; P.W_g = W_g; P.b_g = b_g;
  P.histG = histG; P.membG = membG; P.gt_all = gt_all; P.outg = out + 1;

  k_loop<<<8, 512, LDSSZ, stream>>>(P);
  k_vocab<<<29*VCH, 256, 131072, stream>>>(histG, Wnvb, b_nv, pmps);
  k_combine<<<29, 128, 0, stream>>>(pmps, histG, W_nv, b_nv, gt_all, sentence, loss_part);
  k_fin<<<1, 64, 0, stream>>>(loss_part, out);
}

// Round 5
// 1174.451 us; speedup vs baseline: 4.1108x; 4.1108x over previous
//
#include <hip/hip_runtime.h>
#include <math.h>

#define B_ 128
#define L_ 30
#define M_ 10
#define H_ 256
#define VN_ 32000
#define VCH 10
#define VITER 25     // (VN/VCH)/128

typedef __bf16 bf16;
typedef bf16 bf16x8 __attribute__((ext_vector_type(8)));
typedef float f32x4 __attribute__((ext_vector_type(4)));

#define MFMA(a,b,c) __builtin_amdgcn_mfma_f32_16x16x32_bf16(a, b, c, 0, 0, 0)

__device__ __forceinline__ float rcpf(float x) { return __builtin_amdgcn_rcpf(x); }
__device__ __forceinline__ float sigf(float x) { return rcpf(1.f + __expf(-x)); }
__device__ __forceinline__ float ftanh(float x) {
  float e = __expf(2.f * x);
  return 1.f - 2.f * rcpf(e + 1.f);
}
__device__ __forceinline__ float u2lo(unsigned w) { return __builtin_bit_cast(float, w << 16); }
__device__ __forceinline__ float u2hi(unsigned w) { return __builtin_bit_cast(float, w & 0xffff0000u); }
__device__ __forceinline__ unsigned packbf2(float a, float b) {
  unsigned short lo = __builtin_bit_cast(unsigned short, (bf16)a);
  unsigned short hi = __builtin_bit_cast(unsigned short, (bf16)b);
  return (unsigned)lo | ((unsigned)hi << 16);
}

#if __has_builtin(__builtin_amdgcn_fdot2_f32_bf16)
typedef __bf16 bf16x2 __attribute__((ext_vector_type(2)));
__device__ __forceinline__ float dot2(unsigned x, unsigned w, float c) {
  return __builtin_amdgcn_fdot2_f32_bf16(__builtin_bit_cast(bf16x2, x),
                                         __builtin_bit_cast(bf16x2, w), c, false);
}
#else
__device__ __forceinline__ float dot2(unsigned x, unsigned w, float c) {
  c = fmaf(u2lo(x), u2lo(w), c);
  return fmaf(u2hi(x), u2hi(w), c);
}
#endif

// ---------------------------------------------------------------- weight prep (k-pair packed, n-coalesced)
__global__ __launch_bounds__(256) void k_prep(
    const float* W_ct, const float* W_ih, const float* W_hh,
    const float* W_n, const float* W_k, const float* W_v, const float* W_nv,
    const float* W_hn, const float* W_hk, const float* W_hv,
    const float* W_mk, const float* W_mv, const float* W_g,
    unsigned* WhhP, unsigned* WihP, unsigned* WnkvP, unsigned* WctPH, unsigned* WctP45,
    unsigned* WmP0, unsigned* WmPQ, unsigned* WhdA, unsigned* WhdB, unsigned* WgP,
    bf16* Wnvb) {
  int stride = gridDim.x * blockDim.x;
  int base = blockIdx.x * blockDim.x + threadIdx.x;
  // gates h-part / emb-part: [k2 128][n 1024]
  for (int i = base; i < 131072; i += stride) {
    int k2 = i >> 10, n = i & 1023;
    WhhP[i] = packbf2(W_hh[n*256 + 2*k2], W_hh[n*256 + 2*k2 + 1]);
    WihP[i] = packbf2(W_ih[n*256 + 2*k2], W_ih[n*256 + 2*k2 + 1]);
  }
  // hnkv: [k2 128][n 768]
  for (int i = base; i < 98304; i += stride) {
    int k2 = i / 768, n = i - (i/768)*768;
    const float* s = (n < 256) ? W_n : (n < 512) ? W_k : W_v;
    int nn = n & 255;
    WnkvP[i] = packbf2(s[nn*256 + 2*k2], s[nn*256 + 2*k2 + 1]);
  }
  // W_ct cH segs: [X 3][k2 128][n 256]
  for (int i = base; i < 98304; i += stride) {
    int X = i >> 15, r = i & 32767, k2 = r >> 8, n = r & 255;
    int col = X*256 + 2*k2;
    WctPH[i] = packbf2(W_ct[n*1280 + col], W_ct[n*1280 + col + 1]);
  }
  // W_ct cM segs: [X 2][k2 128][n 256]
  for (int i = base; i < 65536; i += stride) {
    int X = i >> 15, r = i & 32767, k2 = r >> 8, n = r & 255;
    int col = 768 + X*256 + 2*k2;
    WctP45[i] = packbf2(W_ct[n*1280 + col], W_ct[n*1280 + col + 1]);
  }
  // mem-attn prev_h seg: [k2 128][c 32]  (c<10: mk, 16<=c<26: mv)
  for (int i = base; i < 4096; i += stride) {
    int k2 = i >> 5, c = i & 31;
    float x0 = 0.f, x1 = 0.f;
    if (c < 10)              { x0 = W_mk[c*1024 + 2*k2]; x1 = W_mk[c*1024 + 2*k2 + 1]; }
    else if (c >= 16 && c < 26) { int m = c-16; x0 = W_mv[m*1024 + 2*k2]; x1 = W_mv[m*1024 + 2*k2 + 1]; }
    WmP0[i] = packbf2(x0, x1);
  }
  // mem-attn cH segs: [X 3][k2 128][c 32]
  for (int i = base; i < 12288; i += stride) {
    int X = i >> 12, r = i & 4095, k2 = r >> 5, c = r & 31;
    int off = 256 + X*256 + 2*k2;
    float x0 = 0.f, x1 = 0.f;
    if (c < 10)              { x0 = W_mk[c*1024 + off]; x1 = W_mk[c*1024 + off + 1]; }
    else if (c >= 16 && c < 26) { int m = c-16; x0 = W_mv[m*1024 + off]; x1 = W_mv[m*1024 + off + 1]; }
    WmPQ[i] = packbf2(x0, x1);
  }
  // attn dA per-step: [d 30][k2 128][c 128]  (c<96: X=c>>5,l=c&31)
  for (int i = base; i < 491520; i += stride) {
    int d = i >> 14, r = i & 16383, k2 = r >> 7, c = r & 127;
    float x0 = 0.f, x1 = 0.f;
    if (c < 96) {
      int X = c >> 5, l = c & 31;
      if (l < 30) {
        const float* W = (X == 0) ? W_hn : (X == 1) ? W_hk : W_hv;
        x0 = W[l*7936 + d*256 + 2*k2]; x1 = W[l*7936 + d*256 + 2*k2 + 1];
      }
    }
    WhdA[i] = packbf2(x0, x1);
  }
  // attn dB (prev_h seg): [k2 128][c 128]
  for (int i = base; i < 16384; i += stride) {
    int k2 = i >> 7, c = i & 127;
    float x0 = 0.f, x1 = 0.f;
    if (c < 96) {
      int X = c >> 5, l = c & 31;
      if (l < 30) {
        const float* W = (X == 0) ? W_hn : (X == 1) ? W_hk : W_hv;
        x0 = W[l*7936 + 2*k2]; x1 = W[l*7936 + 2*k2 + 1];
      }
    }
    WhdB[i] = packbf2(x0, x1);
  }
  for (int i = base; i < 128; i += stride) WgP[i] = packbf2(W_g[2*i], W_g[2*i+1]);
  for (int i = base; i < VN_*H_; i += stride) Wnvb[i] = (bf16)W_nv[i];
}

// ---------------------------------------------------------------- hoisted emb@W_ih for all 29 steps
__global__ __launch_bounds__(256) void k_pregates(
    const int* sentence, const float* emb, const unsigned* WihP,
    const float* b_ih, const float* b_hh, float* prehg) {
  __shared__ unsigned ep[128];
  int blk = blockIdx.x, t = threadIdx.x;
  int gd = blk >> 7, b = blk & 127;
  int tok = sentence[b*L_ + gd];
  if (t < 128) {
    const float* e = emb + (size_t)tok*H_ + 2*t;
    ep[t] = packbf2(e[0], e[1]);
  }
  __syncthreads();
  #pragma unroll
  for (int i = 0; i < 4; ++i) {
    int n = t + 256*i;
    float a0 = 0.f, a1 = 0.f;
    const unsigned* wp = WihP + n;
    #pragma unroll 8
    for (int k2 = 0; k2 < 128; k2 += 2) {
      a0 = dot2(ep[k2],     wp[k2 << 10],     a0);
      a1 = dot2(ep[k2 + 1], wp[(k2+1) << 10], a1);
    }
    prehg[(size_t)blk*1024 + n] = a0 + a1 + b_ih[n] + b_hh[n];
  }
}

// ---------------------------------------------------------------- recurrence: 128 blocks x 1 batch row, 1024 threads
struct LoopP {
  const int *sentence, *keywords, *categories, *memsz;
  const float *emb;
  const unsigned *WhhP, *WnkvP, *WctPH, *WctP45, *WmP0, *WmPQ, *WhdA, *WhdB, *WgP;
  const float *prehg;
  const float *b_ct, *b_hn, *b_hk, *b_hv, *b_mk, *b_mv, *b_g;
  unsigned* hNb;     // [29*128][128] u32 (bf16 pairs)
  float* gt_all;     // [29*128]
  float* outg;       // [128][30]
};

__global__ __launch_bounds__(1024) void k_loop(LoopP p) {
  extern __shared__ unsigned Su[];
  float* Sf = (float*)Su;
  const int t = threadIdx.x, b = blockIdx.x;
  // element (u32/f32) offsets in LDS
  enum { PH = 0,          // u32 [3][30][128] bf16-pair projections (c0 segs)
         QM = 11520,      // f32 [3][30][32]  mem-attn projections
         P45 = 14400,     // u32 [2][10][128] mem->c0 projections
         MB = 16960,      // u32 [2][10][128] memb pairs (init only)
         GA = 19520,      // f32 [1024] gates
         HP = 20544,      // u32 [128]  h pairs
         HV = 20672,      // u32 [3][128] hN/hK/hV pairs (latest slot)
         SW = 21056, ACA = 21152, SWM = 21248, M0 = 21280,
         DA = 21312, DB = 21440,
         BCT = 21568, BH = 21824, BM = 21920, BG = 21952 };

  // ===== init =====
  for (int i = t; i < 2560; i += 1024) {
    int X = i / 1280, r = i - X*1280, m = r >> 7, j = r & 127;
    int ms = p.memsz[b];
    int idx = (X == 0 ? p.keywords : p.categories)[b*M_ + m];
    unsigned u = 0;
    if (m < ms) {
      const float* e = p.emb + (size_t)idx*H_ + 2*j;
      u = packbf2(e[0], e[1]);
    }
    Su[MB + i] = u;
  }
  if (t < 256) Sf[BCT + t] = p.b_ct[t];
  if (t < 96) {
    int X = t >> 5, l = t & 31;
    const float* bh = (X == 0) ? p.b_hn : (X == 1) ? p.b_hk : p.b_hv;
    Sf[BH + t] = (l < 30) ? bh[l] : 0.f;
    Sf[ACA + t] = 0.f;
  }
  if (t < 32) {
    float v = 0.f;
    if (t < 10) v = p.b_mk[t];
    else if (t >= 16 && t < 26) v = p.b_mv[t - 16];
    Sf[BM + t] = v;
  }
  if (t == 0) { Sf[BG] = p.b_g[0]; p.outg[b*L_] = 0.f; }
  __syncthreads();
  if (t < 128) {
    float a0 = 0.f, a1 = 0.f;
    #pragma unroll
    for (int q = 0; q < 20; ++q) {
      unsigned u = Su[MB + q*128 + t];
      a0 += u2lo(u); a1 += u2hi(u);
    }
    float msf = (float)p.memsz[b];
    float ih0 = a0 / (2.f * msf), ih1 = a1 / (2.f * msf);
    unsigned up = packbf2(ih0, ih1);
    Su[HP + t] = up;
    Su[HV + t] = up; Su[HV + 128 + t] = up; Su[HV + 256 + t] = up;
  }
  // P45[m][n-pair] = mem[m] @ Wct seg {4,5}
  for (int q = t; q < 2560; q += 1024) {
    int X = q / 1280, r = q - X*1280, m = r >> 7, j = r & 127;
    float a0 = 0.f, a1 = 0.f;
    const uint2* wp = (const uint2*)(p.WctP45 + (X << 15)) + j;
    const unsigned* mb = Su + MB + X*1280 + m*128;
    #pragma unroll 4
    for (int k2 = 0; k2 < 128; ++k2) {
      uint2 w = wp[k2 << 7];
      unsigned u = mb[k2];
      a0 = dot2(u, w.x, a0);
      a1 = dot2(u, w.y, a1);
    }
    Su[P45 + q] = packbf2(a0, a1);
  }
  __syncthreads();

  for (int di = 1; di < L_; ++di) {
    // ---- R1: gates (all threads) + slot projections + logits ----
    {
      const float pre = p.prehg[(size_t)(((di-1) << 7) | b)*1024 + t];
      float e0 = 0.f, e1 = 0.f;
      const unsigned* wp = p.WhhP + t;
      #pragma unroll 8
      for (int k2 = 0; k2 < 128; k2 += 2) {
        e0 = dot2(Su[HP + k2],     wp[k2 << 10],     e0);
        e1 = dot2(Su[HP + k2 + 1], wp[(k2+1) << 10], e1);
      }
      Sf[GA + t] = pre + e0 + e1;
    }
    if (t < 128) {            // dA (uses hist slot di-1 = HV)
      float a = 0.f;
      const unsigned* wp = p.WhdA + ((size_t)di << 14) + t;
      const unsigned* hv = Su + HV + ((t >> 5) << 7);
      #pragma unroll 8
      for (int k2 = 0; k2 < 128; ++k2) a = dot2(hv[k2 & 127], wp[k2 << 7], a);
      Sf[DA + t] = a;
    } else if (t < 256) {     // dB (uses prev h)
      int c = t - 128;
      float a = 0.f;
      const unsigned* wp = p.WhdB + c;
      #pragma unroll 8
      for (int k2 = 0; k2 < 128; ++k2) a = dot2(Su[HP + k2], wp[k2 << 7], a);
      Sf[DB + c] = a;
    } else if (t < 640) {     // PH append: project slot di-1
      int q = t - 256, X = q >> 7, j = q & 127;
      float a0 = 0.f, a1 = 0.f;
      const unsigned* hv = Su + HV + (X << 7);
      const uint2* wp = (const uint2*)(p.WctPH + (X << 15)) + j;
      #pragma unroll 4
      for (int k2 = 0; k2 < 128; ++k2) {
        uint2 w = wp[k2 << 7];
        a0 = dot2(hv[k2], w.x, a0);
        a1 = dot2(hv[k2], w.y, a1);
      }
      Su[PH + (X*30 + di-1)*128 + j] = packbf2(a0, a1);
    } else if (t < 736) {     // QM append
      int q = t - 640, X = q >> 5, c = q & 31;
      float a = 0.f;
      const unsigned* wp = p.WmPQ + (X << 12) + c;
      const unsigned* hv = Su + HV + (X << 7);
      #pragma unroll 8
      for (int k2 = 0; k2 < 128; ++k2) a = dot2(hv[k2], wp[k2 << 5], a);
      Sf[QM + (X*30 + di-1)*32 + c] = a;
    } else if (t >= 768 && t < 800) {  // mem0 (prev_h part of mem-attn)
      int c = t - 768;
      float a = 0.f;
      const unsigned* wp = p.WmP0 + c;
      #pragma unroll 8
      for (int k2 = 0; k2 < 128; ++k2) a = dot2(Su[HP + k2], wp[k2 << 5], a);
      Sf[M0 + c] = a;
    }
    __syncthreads();
    // ---- R2: sw ----
    if (t < 96) {
      float a = Sf[ACA + t] + Sf[DA + t];
      Sf[ACA + t] = a;
      Sf[SW + t] = ftanh(a + Sf[DB + t] + Sf[BH + t]);
    }
    __syncthreads();
    // ---- R3: swm ----
    if (t < 32) {
      bool valid = (t < 10) || (t >= 16 && t < 26);
      if (valid) {
        float a = Sf[M0 + t] + Sf[BM + t];
        for (int X = 0; X < 3; ++X) {
          const float* swp = Sf + SW + X*32;
          const float* qmp = Sf + QM + X*960 + t;
          for (int l = 0; l < di; ++l) a = fmaf(swp[l], qmp[l*32], a);
        }
        Sf[SWM + t] = ftanh(a);
      }
    }
    __syncthreads();
    // ---- R4: c0 + LSTM cell (pairs) ----
    if (t < 128) {
      float a0 = Sf[BCT + 2*t], a1 = Sf[BCT + 2*t + 1];
      for (int X = 0; X < 3; ++X) {
        const float* swp = Sf + SW + X*32;
        const unsigned* php = Su + PH + X*3840 + t;
        for (int l = 0; l < di; ++l) {
          float s = swp[l];
          unsigned u = php[l*128];
          a0 = fmaf(s, u2lo(u), a0);
          a1 = fmaf(s, u2hi(u), a1);
        }
      }
      #pragma unroll
      for (int m = 0; m < 10; ++m) {
        float sk = Sf[SWM + m], sv = Sf[SWM + 16 + m];
        unsigned uk = Su[P45 + m*128 + t], uv = Su[P45 + 1280 + m*128 + t];
        a0 = fmaf(sk, u2lo(uk), a0); a1 = fmaf(sk, u2hi(uk), a1);
        a0 = fmaf(sv, u2lo(uv), a0); a1 = fmaf(sv, u2hi(uv), a1);
      }
      int n0 = 2*t;
      float gi0 = Sf[GA+n0],   gf0 = Sf[GA+256+n0], gg0 = Sf[GA+512+n0], go0 = Sf[GA+768+n0];
      float gi1 = Sf[GA+n0+1], gf1 = Sf[GA+257+n0], gg1 = Sf[GA+513+n0], go1 = Sf[GA+769+n0];
      float cc0 = sigf(gf0)*a0 + sigf(gi0)*ftanh(gg0);
      float cc1 = sigf(gf1)*a1 + sigf(gi1)*ftanh(gg1);
      float h0 = sigf(go0)*ftanh(cc0);
      float h1 = sigf(go1)*ftanh(cc1);
      Su[HP + t] = packbf2(h0, h1);
    }
    __syncthreads();
    // ---- R5: hN/hK/hV + gt ----
    if (t < 384) {
      int X = t >> 7, j = t & 127;
      float a0 = 0.f, a1 = 0.f;
      const uint2* wp = (const uint2*)p.WnkvP + t;
      #pragma unroll 4
      for (int k2 = 0; k2 < 128; ++k2) {
        uint2 w = wp[k2*384];
        unsigned u = Su[HP + k2];
        a0 = dot2(u, w.x, a0);
        a1 = dot2(u, w.y, a1);
      }
      unsigned up = packbf2(a0, a1);
      Su[HV + t] = up;
      if (X == 0) p.hNb[(size_t)(((di-1) << 7) | b)*128 + j] = up;
    } else if (t >= 448 && t < 512) {
      int j = t - 448;
      float a = dot2(Su[HP + 2*j], p.WgP[2*j], 0.f);
      a = dot2(Su[HP + 2*j + 1], p.WgP[2*j + 1], a);
      #pragma unroll
      for (int o = 1; o < 64; o <<= 1) a += __shfl_xor(a, o);
      if (j == 0) {
        float g = sigf(a + Sf[BG]);
        p.gt_all[((di-1) << 7) | b] = g;
        p.outg[b*L_ + di] = g;
      }
    }
    __syncthreads();
  }
}

// ---------------------------------------------------------------- batched vocab GEMM + streaming LSE
__global__ __launch_bounds__(256) void k_vocab(
    const bf16* hNb, const bf16* Wnvb, const float* b_nv, float2* pmps) {
  extern __shared__ char smv[];
  char* Al = smv;             // 128 x 256 bf16, swizzled
  char* Bl = smv + 65536;     // 128 x 256 bf16, swizzled
  int blk = blockIdx.x;
  int tile = blk / VCH, ch = blk - tile*VCH;
  int t = threadIdx.x, wid = t >> 6, lane = t & 63;
  for (int i = t; i < 128*32; i += 256) {
    int r = i >> 5, c8 = i & 31;
    int4 v = *(const int4*)(hNb + ((size_t)tile*128 + r)*H_ + c8*8);
    *(int4*)(Al + ((r*512 + c8*16) ^ ((r&7)<<4))) = v;
  }
  __syncthreads();
  bf16x8 afr[8][2];
  #pragma unroll
  for (int kk = 0; kk < 8; ++kk) {
    int kb2 = kk*64 + (lane>>4)*16;
    #pragma unroll
    for (int fi = 0; fi < 2; ++fi) {
      int m = wid*32 + fi*16 + (lane & 15);
      afr[kk][fi] = *(const bf16x8*)(Al + ((m*512 + kb2) ^ ((m&7)<<4)));
    }
  }
  float Mrun[2][4], Srun[2][4];
  #pragma unroll
  for (int fi = 0; fi < 2; ++fi)
    #pragma unroll
    for (int r = 0; r < 4; ++r) { Mrun[fi][r] = -1e30f; Srun[fi][r] = 0.f; }
  int v0 = ch * (VN_/VCH);
  for (int it = 0; it < VITER; ++it) {
    for (int i = t; i < 128*32; i += 256) {
      int r = i >> 5, c8 = i & 31;
      int4 v = *(const int4*)(Wnvb + (size_t)(v0 + it*128 + r)*H_ + c8*8);
      *(int4*)(Bl + ((r*512 + c8*16) ^ ((r&7)<<4))) = v;
    }
    __syncthreads();
    f32x4 acc[2][8] = {};
    #pragma unroll
    for (int kk = 0; kk < 8; ++kk) {
      int kb2 = kk*64 + (lane>>4)*16;
      bf16x8 bfr[8];
      #pragma unroll
      for (int fj = 0; fj < 8; ++fj) {
        int n = fj*16 + (lane & 15);
        bfr[fj] = *(const bf16x8*)(Bl + ((n*512 + kb2) ^ ((n&7)<<4)));
      }
      #pragma unroll
      for (int fi = 0; fi < 2; ++fi)
        #pragma unroll
        for (int fj = 0; fj < 8; ++fj)
          acc[fi][fj] = MFMA(afr[kk][fi], bfr[fj], acc[fi][fj]);
    }
    float bb[8];
    #pragma unroll
    for (int fj = 0; fj < 8; ++fj) bb[fj] = b_nv[v0 + it*128 + fj*16 + (lane & 15)];
    #pragma unroll
    for (int fi = 0; fi < 2; ++fi)
      #pragma unroll
      for (int r = 0; r < 4; ++r) {
        float mi = acc[fi][0][r] + bb[0];
        #pragma unroll
        for (int fj = 1; fj < 8; ++fj) mi = fmaxf(mi, acc[fi][fj][r] + bb[fj]);
        for (int o = 1; o < 16; o <<= 1) mi = fmaxf(mi, __shfl_xor(mi, o));
        float si = 0.f;
        #pragma unroll
        for (int fj = 0; fj < 8; ++fj) si += __expf(acc[fi][fj][r] + bb[fj] - mi);
        for (int o = 1; o < 16; o <<= 1) si += __shfl_xor(si, o);
        float M2 = fmaxf(Mrun[fi][r], mi);
        Srun[fi][r] = Srun[fi][r]*__expf(Mrun[fi][r] - M2) + si*__expf(mi - M2);
        Mrun[fi][r] = M2;
      }
    __syncthreads();
  }
  #pragma unroll
  for (int fi = 0; fi < 2; ++fi)
    #pragma unroll
    for (int r = 0; r < 4; ++r)
      if ((lane & 15) == 0) {
        int row = wid*32 + fi*16 + (lane>>4)*4 + r;
        int g = tile*128 + row;
        pmps[(size_t)g*VCH + ch] = make_float2(Mrun[fi][r], Srun[fi][r]);
      }
}

// ---------------------------------------------------------------- per-step loss combine
__global__ __launch_bounds__(128) void k_combine(
    const float2* pmps, const unsigned* hNb, const float* W_nv, const float* b_nv,
    const float* gt_all, const int* sentence, float* loss_part) {
  __shared__ float red[128];
  int tile = blockIdx.x, bb = threadIdx.x;
  int g = tile*128 + bb;
  float M = -1e30f, Ssum = 0.f;
  #pragma unroll
  for (int c = 0; c < VCH; ++c) {
    float2 v = pmps[(size_t)g*VCH + c];
    float M2 = fmaxf(M, v.x);
    Ssum = Ssum*__expf(M - M2) + v.y*__expf(v.x - M2);
    M = M2;
  }
  int tok = sentence[bb*L_ + tile + 1];
  float z = b_nv[tok];
  const unsigned* hu = hNb + (size_t)g*128;
  const float* wr = W_nv + (size_t)tok*H_;
  #pragma unroll 8
  for (int k = 0; k < 128; ++k) {
    unsigned w2 = hu[k];
    z += u2lo(w2)*wr[2*k] + u2hi(w2)*wr[2*k + 1];
  }
  float term = -(z - M - __logf(Ssum) + __logf(gt_all[g]));
  red[bb] = term;
  __syncthreads();
  for (int o = 64; o > 0; o >>= 1) {
    if (bb < o) red[bb] += red[bb + o];
    __syncthreads();
  }
  if (bb == 0) loss_part[tile] = red[0];
}

__global__ __launch_bounds__(64) void k_fin(const float* lp, float* out) {
  int t = threadIdx.x;
  float v = (t < 29) ? lp[t] : 0.f;
  for (int o = 1; o < 64; o <<= 1) v += __shfl_xor(v, o);
  if (t == 0) out[0] = v;
}

// ---------------------------------------------------------------- launch
extern "C" void kernel_launch(void* const* d_in, const int* in_sizes, int n_in,
                              void* d_out, int out_size, void* d_ws, size_t ws_size,
                              hipStream_t stream) {
  const int* sentence  = (const int*)d_in[0];
  const int* keywords  = (const int*)d_in[1];
  const int* categories= (const int*)d_in[2];
  const int* memsz     = (const int*)d_in[3];
  const float* emb  = (const float*)d_in[5];
  const float* W_ct = (const float*)d_in[6];
  const float* b_ct = (const float*)d_in[7];
  const float* W_ih = (const float*)d_in[8];
  const float* W_hh = (const float*)d_in[9];
  const float* b_ih = (const float*)d_in[10];
  const float* b_hh = (const float*)d_in[11];
  const float* W_n  = (const float*)d_in[12];
  const float* W_k  = (const float*)d_in[13];
  const float* W_v  = (const float*)d_in[14];
  const float* W_nv = (const float*)d_in[15];
  const float* b_nv = (const float*)d_in[16];
  const float* W_g  = (const float*)d_in[17];
  const float* b_g  = (const float*)d_in[18];
  const float* W_hn = (const float*)d_in[19];
  const float* b_hn = (const float*)d_in[20];
  const float* W_hk = (const float*)d_in[21];
  const float* b_hk = (const float*)d_in[22];
  const float* W_hv = (const float*)d_in[23];
  const float* b_hv = (const float*)d_in[24];
  const float* W_mk = (const float*)d_in[25];
  const float* b_mk = (const float*)d_in[26];
  const float* W_mv = (const float*)d_in[27];
  const float* b_mv = (const float*)d_in[28];
  float* out = (float*)d_out;

  char* wsp = (char*)d_ws;
  size_t off = 0;
  auto alloc = [&](size_t bytes) -> void* {
    void* pp = wsp + off;
    off = (off + bytes + 255) & ~(size_t)255;
    return pp;
  };
  unsigned* WhhP   = (unsigned*)alloc((size_t)131072*4);
  unsigned* WihP   = (unsigned*)alloc((size_t)131072*4);
  unsigned* WnkvP  = (unsigned*)alloc((size_t)98304*4);
  unsigned* WctPH  = (unsigned*)alloc((size_t)98304*4);
  unsigned* WctP45 = (unsigned*)alloc((size_t)65536*4);
  unsigned* WmP0   = (unsigned*)alloc((size_t)4096*4);
  unsigned* WmPQ   = (unsigned*)alloc((size_t)12288*4);
  unsigned* WhdA   = (unsigned*)alloc((size_t)491520*4);
  unsigned* WhdB   = (unsigned*)alloc((size_t)16384*4);
  unsigned* WgP    = (unsigned*)alloc((size_t)128*4);
  bf16* Wnvb       = (bf16*)alloc((size_t)VN_*H_*2);
  float* prehg     = (float*)alloc((size_t)29*B_*1024*4);
  unsigned* hNb    = (unsigned*)alloc((size_t)29*B_*128*4);
  float* gt_all    = (float*)alloc((size_t)29*B_*4);
  float2* pmps     = (float2*)alloc((size_t)29*B_*VCH*8);
  float* loss_part = (float*)alloc(29*4);

  k_prep<<<1024, 256, 0, stream>>>(W_ct, W_ih, W_hh, W_n, W_k, W_v, W_nv,
      W_hn, W_hk, W_hv, W_mk, W_mv, W_g,
      WhhP, WihP, WnkvP, WctPH, WctP45, WmP0, WmPQ, WhdA, WhdB, WgP, Wnvb);
  k_pregates<<<29*B_, 256, 0, stream>>>(sentence, emb, WihP, b_ih, b_hh, prehg);

  LoopP P;
  P.sentence = sentence; P.keywords = keywords; P.categories = categories; P.memsz = memsz;
  P.emb = emb;
  P.WhhP = WhhP; P.WnkvP = WnkvP; P.WctPH = WctPH; P.WctP45 = WctP45;
  P.WmP0 = WmP0; P.WmPQ = WmPQ; P.WhdA = WhdA; P.WhdB = WhdB; P.WgP = WgP;
  P.prehg = prehg;
  P.b_ct = b_ct; P.b_hn = b_hn; P.b_hk = b_hk; P.b_hv = b_hv;
  P.b_mk = b_mk; P.b_mv = b_mv; P.b_g = b_g;
  P.hNb = hNb; P.gt_all = gt_all; P.outg = out + 1;

  k_loop<<<B_, 1024, 87812, stream>>>(P);
  k_vocab<<<29*VCH, 256, 131072, stream>>>((const bf16*)hNb, Wnvb, b_nv, pmps);
  k_combine<<<29, 128, 0, stream>>>(pmps, hNb, W_nv, b_nv, gt_all, sentence, loss_part);
  k_fin<<<1, 64, 0, stream>>>(loss_part, out);
}